// Round 2
// baseline (5086.258 us; speedup 1.0000x reference)
//
#include <hip/hip_runtime.h>
#include <hip/hip_bf16.h>
#include <math.h>

constexpr int BATCH = 4;
constexpr int SEQ   = 2048;
constexpr int HID   = 2048;
constexpr int NHEAD = 8;
constexpr int NKVH  = 1;
constexpr int HD    = 256;
constexpr int QKVN  = (NHEAD + 2 * NKVH) * HD;  // 2560
constexpr float SCL = 0.0625f;                   // 256^-0.5
constexpr int GQ    = 8;                         // q rows per wave in attention

// hardware LDS fence within a wave: all outstanding LDS ops complete,
// compiler may not reorder memory ops across it
__device__ __forceinline__ void lds_fence_wave() {
  __asm__ volatile("s_waitcnt lgkmcnt(0)" ::: "memory");
}

// ---------- generic tiled GEMM: C[M,N] = A[M,K] * B[K,N], fp32 accumulate ----------
__global__ __launch_bounds__(256)
void gemm_kernel(const float* __restrict__ A, const float* __restrict__ Bm,
                 float* __restrict__ C, int M, int N, int K) {
  constexpr int BM = 128, BN = 128, BK = 16;
  __shared__ float As[BK][BM + 4];
  __shared__ float Bs[BK][BN + 4];
  const int bm = blockIdx.y * BM;
  const int bn = blockIdx.x * BN;
  const int tid = threadIdx.x;
  const int tx = tid & 15;   // 0..15 -> 8 cols each
  const int ty = tid >> 4;   // 0..15 -> 8 rows each

  float acc[8][8];
#pragma unroll
  for (int i = 0; i < 8; ++i)
#pragma unroll
    for (int j = 0; j < 8; ++j) acc[i][j] = 0.f;

  const int arow = tid >> 2;         // 0..63
  const int akc  = (tid & 3) * 4;    // 0,4,8,12
  const int bkr  = tid >> 5;         // 0..7
  const int bnc  = (tid & 31) * 4;   // 0..124

  for (int k0 = 0; k0 < K; k0 += BK) {
    // A tile: 128 rows x 16 k
#pragma unroll
    for (int r = 0; r < 2; ++r) {
      const int m = arow + r * 64;
      float4 v = *(const float4*)(A + (size_t)(bm + m) * K + k0 + akc);
      As[akc + 0][m] = v.x; As[akc + 1][m] = v.y;
      As[akc + 2][m] = v.z; As[akc + 3][m] = v.w;
    }
    // B tile: 16 k x 128 cols
#pragma unroll
    for (int r = 0; r < 2; ++r) {
      const int k = bkr + r * 8;
      float4 v = *(const float4*)(Bm + (size_t)(k0 + k) * N + bn + bnc);
      *(float4*)&Bs[k][bnc] = v;
    }
    __syncthreads();

#pragma unroll
    for (int kk = 0; kk < BK; ++kk) {
      float4 a0 = *(const float4*)&As[kk][ty * 8];
      float4 a1 = *(const float4*)&As[kk][ty * 8 + 4];
      float4 b0 = *(const float4*)&Bs[kk][tx * 8];
      float4 b1 = *(const float4*)&Bs[kk][tx * 8 + 4];
      float a[8] = {a0.x, a0.y, a0.z, a0.w, a1.x, a1.y, a1.z, a1.w};
      float b[8] = {b0.x, b0.y, b0.z, b0.w, b1.x, b1.y, b1.z, b1.w};
#pragma unroll
      for (int i = 0; i < 8; ++i)
#pragma unroll
        for (int j = 0; j < 8; ++j) acc[i][j] = fmaf(a[i], b[j], acc[i][j]);
    }
    __syncthreads();
  }

#pragma unroll
  for (int i = 0; i < 8; ++i) {
    float* cp = C + (size_t)(bm + ty * 8 + i) * N + bn + tx * 8;
#pragma unroll
    for (int j = 0; j < 8; ++j) cp[j] = acc[i][j];
  }
}

// ---------- RoPE on q heads + k head; also writes K transposed Kt[b][d][s] ----------
__global__ __launch_bounds__(128)
void rope_kernel(const int* __restrict__ positions, float* __restrict__ qkv,
                 float* __restrict__ Kt) {
  const int bs = blockIdx.x;          // b*SEQ + s
  const int b  = bs / SEQ;
  const int s  = bs % SEQ;
  const int h  = blockIdx.y;          // 0..NHEAD-1 = q heads, NHEAD = k head
  const int i  = threadIdx.x;         // 0..127 (pair index)

  const float pos = (float)positions[s];
  const float inv_freq = powf(10000.0f, -(float)i / 128.0f);
  const float ang = pos * inv_freq;
  float sn, cs;
  sincosf(ang, &sn, &cs);

  const size_t base = (size_t)bs * QKVN + (size_t)h * HD;
  const float x1 = qkv[base + i];
  const float x2 = qkv[base + 128 + i];
  const float r1 = x1 * cs - x2 * sn;
  const float r2 = x2 * cs + x1 * sn;
  qkv[base + i] = r1;
  qkv[base + 128 + i] = r2;
  if (h == NHEAD) {
    Kt[((size_t)b * HD + i) * SEQ + s]       = r1;
    Kt[((size_t)b * HD + i + 128) * SEQ + s] = r2;
  }
}

// ---------- flash attention: 1 wave handles GQ consecutive q rows of one (b,h) ----------
__global__ __launch_bounds__(256)
void attn_kernel(const float* __restrict__ qkv, const float* __restrict__ Kt,
                 float* __restrict__ attn) {
  __shared__ float qs[4][GQ][HD];     // 32 KB
  __shared__ float ps[4][64][GQ];     // 8 KB

  const int tid  = threadIdx.x;
  const int w    = tid >> 6;
  const int lane = tid & 63;
  const int group = blockIdx.x * 4 + w;

  constexpr int GPH = SEQ / GQ;              // 256 groups per (b,h)
  const int b   = group / (NHEAD * GPH);
  const int rem = group % (NHEAD * GPH);
  const int h   = rem / GPH;
  const int q0  = (rem % GPH) * GQ;

  // load GQ query rows into LDS, pre-scaled
  const float* qbase = qkv + ((size_t)(b * SEQ + q0)) * QKVN + (size_t)h * HD;
#pragma unroll
  for (int g = 0; g < GQ; ++g) {
    float4 v = *(const float4*)(qbase + (size_t)g * QKVN + lane * 4);
    v.x *= SCL; v.y *= SCL; v.z *= SCL; v.w *= SCL;
    *(float4*)&qs[w][g][lane * 4] = v;
  }
  lds_fence_wave();

  float m[GQ], l[GQ];
  float4 o[GQ];
#pragma unroll
  for (int g = 0; g < GQ; ++g) {
    m[g] = -1e30f; l[g] = 0.f;
    o[g].x = 0.f; o[g].y = 0.f; o[g].z = 0.f; o[g].w = 0.f;
  }

  const float* KtB   = Kt + (size_t)b * HD * SEQ;
  const float* Vbase = qkv + (size_t)(b * SEQ) * QKVN + (size_t)(NHEAD + NKVH) * HD;
  const int qmax = q0 + GQ - 1;
  const int ntiles = qmax / 64 + 1;

  for (int t = 0; t < ntiles; ++t) {
    const int k0 = t * 64;
    const int key = k0 + lane;
    float sc[GQ];
#pragma unroll
    for (int g = 0; g < GQ; ++g) sc[g] = 0.f;

    const float* kp = KtB + key;
#pragma unroll 4
    for (int d4 = 0; d4 < HD; d4 += 4) {
      const float k0v = kp[(size_t)(d4 + 0) * SEQ];
      const float k1v = kp[(size_t)(d4 + 1) * SEQ];
      const float k2v = kp[(size_t)(d4 + 2) * SEQ];
      const float k3v = kp[(size_t)(d4 + 3) * SEQ];
#pragma unroll
      for (int g = 0; g < GQ; ++g) {
        float4 qv = *(const float4*)&qs[w][g][d4];
        sc[g] = fmaf(qv.x, k0v, sc[g]);
        sc[g] = fmaf(qv.y, k1v, sc[g]);
        sc[g] = fmaf(qv.z, k2v, sc[g]);
        sc[g] = fmaf(qv.w, k3v, sc[g]);
      }
    }

    // online softmax per q row
#pragma unroll
    for (int g = 0; g < GQ; ++g) {
      const int q = q0 + g;
      float s = (key <= q) ? sc[g] : -1e30f;
      float mx = s;
#pragma unroll
      for (int off = 32; off >= 1; off >>= 1) mx = fmaxf(mx, __shfl_xor(mx, off));
      const float mnew = fmaxf(m[g], mx);
      const float alpha = __expf(m[g] - mnew);
      const float p = __expf(s - mnew);
      float psum = p;
#pragma unroll
      for (int off = 32; off >= 1; off >>= 1) psum += __shfl_xor(psum, off);
      l[g] = l[g] * alpha + psum;
      m[g] = mnew;
      o[g].x *= alpha; o[g].y *= alpha; o[g].z *= alpha; o[g].w *= alpha;
      ps[w][lane][g] = p;
    }
    lds_fence_wave();

    // PV: lane owns d = lane*4..+3
    const float* vp = Vbase + (size_t)k0 * QKVN + lane * 4;
#pragma unroll 8
    for (int j = 0; j < 64; ++j) {
      float4 v = *(const float4*)(vp + (size_t)j * QKVN);
      float4 p0 = *(const float4*)&ps[w][j][0];
      float4 p1 = *(const float4*)&ps[w][j][4];
      o[0].x = fmaf(p0.x, v.x, o[0].x); o[0].y = fmaf(p0.x, v.y, o[0].y);
      o[0].z = fmaf(p0.x, v.z, o[0].z); o[0].w = fmaf(p0.x, v.w, o[0].w);
      o[1].x = fmaf(p0.y, v.x, o[1].x); o[1].y = fmaf(p0.y, v.y, o[1].y);
      o[1].z = fmaf(p0.y, v.z, o[1].z); o[1].w = fmaf(p0.y, v.w, o[1].w);
      o[2].x = fmaf(p0.z, v.x, o[2].x); o[2].y = fmaf(p0.z, v.y, o[2].y);
      o[2].z = fmaf(p0.z, v.z, o[2].z); o[2].w = fmaf(p0.z, v.w, o[2].w);
      o[3].x = fmaf(p0.w, v.x, o[3].x); o[3].y = fmaf(p0.w, v.y, o[3].y);
      o[3].z = fmaf(p0.w, v.z, o[3].z); o[3].w = fmaf(p0.w, v.w, o[3].w);
      o[4].x = fmaf(p1.x, v.x, o[4].x); o[4].y = fmaf(p1.x, v.y, o[4].y);
      o[4].z = fmaf(p1.x, v.z, o[4].z); o[4].w = fmaf(p1.x, v.w, o[4].w);
      o[5].x = fmaf(p1.y, v.x, o[5].x); o[5].y = fmaf(p1.y, v.y, o[5].y);
      o[5].z = fmaf(p1.y, v.z, o[5].z); o[5].w = fmaf(p1.y, v.w, o[5].w);
      o[6].x = fmaf(p1.z, v.x, o[6].x); o[6].y = fmaf(p1.z, v.y, o[6].y);
      o[6].z = fmaf(p1.z, v.z, o[6].z); o[6].w = fmaf(p1.z, v.w, o[6].w);
      o[7].x = fmaf(p1.w, v.x, o[7].x); o[7].y = fmaf(p1.w, v.y, o[7].y);
      o[7].z = fmaf(p1.w, v.z, o[7].z); o[7].w = fmaf(p1.w, v.w, o[7].w);
    }
  }

  // normalize + write attn[b][q][h*HD + d]
#pragma unroll
  for (int g = 0; g < GQ; ++g) {
    const float inv = 1.0f / l[g];
    float4 r = o[g];
    r.x *= inv; r.y *= inv; r.z *= inv; r.w *= inv;
    *(float4*)(attn + (size_t)(b * SEQ + q0 + g) * HID + (size_t)h * HD + lane * 4) = r;
  }
}

// ---------- launch ----------
extern "C" void kernel_launch(void* const* d_in, const int* in_sizes, int n_in,
                              void* d_out, int out_size, void* d_ws, size_t ws_size,
                              hipStream_t stream) {
  const float* hidden  = (const float*)d_in[0];
  const int* positions = (const int*)d_in[1];
  const float* w_qkv   = (const float*)d_in[2];
  const float* w_o     = (const float*)d_in[3];
  float* out           = (float*)d_out;

  float* qkv  = (float*)d_ws;                          // 8192*2560 fp32  (~84 MB)
  float* Kt   = qkv + (size_t)BATCH * SEQ * QKVN;      // 4*256*2048 fp32 (~8 MB)
  float* attn = Kt + (size_t)BATCH * HD * SEQ;         // 8192*2048 fp32  (~67 MB)

  const int M = BATCH * SEQ;  // 8192

  // 1) QKV projection: hidden (M x HID) @ w_qkv (HID x QKVN) -> qkv fp32
  dim3 g1(QKVN / 128, M / 128);
  gemm_kernel<<<g1, 256, 0, stream>>>(hidden, w_qkv, qkv, M, QKVN, HID);

  // 2) RoPE on q heads + k head; Kt transposed copy
  rope_kernel<<<dim3(BATCH * SEQ, NHEAD + 1), 128, 0, stream>>>(positions, qkv, Kt);

  // 3) causal flash attention -> attn fp32 (M x HID)
  const int ngroups = BATCH * NHEAD * SEQ / GQ;  // 8192
  attn_kernel<<<ngroups / 4, 256, 0, stream>>>(qkv, Kt, attn);

  // 4) output projection: attn (M x HID) @ w_o (HID x HID) -> out fp32
  dim3 g2(HID / 128, M / 128);
  gemm_kernel<<<g2, 256, 0, stream>>>(attn, w_o, out, M, HID, HID);
}

// Round 3
// 613.260 us; speedup vs baseline: 8.2938x; 8.2938x over previous
//
#include <hip/hip_runtime.h>
#include <math.h>

constexpr int BATCH = 4;
constexpr int SEQ   = 2048;
constexpr int HID   = 2048;
constexpr int NHEAD = 8;
constexpr int HD    = 256;
constexpr int QKVN  = (NHEAD + 2) * HD;          // 2560
constexpr float SCL = 0.0625f;                   // 256^-0.5

typedef __bf16 bf16_t;
typedef __bf16 bf16x8 __attribute__((ext_vector_type(8)));
typedef float  f32x4  __attribute__((ext_vector_type(4)));

__device__ __forceinline__ f32x4 zero4() {
  f32x4 z; z[0] = 0.f; z[1] = 0.f; z[2] = 0.f; z[3] = 0.f; return z;
}

__device__ __forceinline__ f32x4 mfma16(bf16x8 a, bf16x8 b, f32x4 c) {
  return __builtin_amdgcn_mfma_f32_16x16x32_bf16(a, b, c, 0, 0, 0);
}

// async global->LDS, 16B per lane. lds must be wave-uniform base; HW adds lane*16.
__device__ __forceinline__ void gl2lds16(const void* g, void* lds) {
  typedef __attribute__((address_space(1))) void* gp_t;
  typedef __attribute__((address_space(3))) void* lp_t;
  __builtin_amdgcn_global_load_lds((gp_t)(size_t)g,
                                   (lp_t)(unsigned int)(size_t)lds, 16, 0, 0);
}

__device__ __forceinline__ float rmax16(float v) {
#pragma unroll
  for (int o = 1; o < 16; o <<= 1) v = fmaxf(v, __shfl_xor(v, o));
  return v;
}
__device__ __forceinline__ float rsum16(float v) {
#pragma unroll
  for (int o = 1; o < 16; o <<= 1) v += __shfl_xor(v, o);
  return v;
}

// ---------- fp32 -> bf16 bulk convert (8 elems/thread) ----------
__global__ __launch_bounds__(256)
void cvt_bf16_kernel(const float* __restrict__ in, bf16_t* __restrict__ out) {
  const int i = blockIdx.x * 256 + threadIdx.x;
  const float4 a = ((const float4*)in)[i * 2];
  const float4 b = ((const float4*)in)[i * 2 + 1];
  bf16x8 o;
  o[0] = (bf16_t)a.x; o[1] = (bf16_t)a.y; o[2] = (bf16_t)a.z; o[3] = (bf16_t)a.w;
  o[4] = (bf16_t)b.x; o[5] = (bf16_t)b.y; o[6] = (bf16_t)b.z; o[7] = (bf16_t)b.w;
  ((bf16x8*)out)[i] = o;
}

// ---------- w[K][N] fp32 -> wT[N][K] bf16, 64x64 tiles ----------
__global__ __launch_bounds__(256)
void transw_kernel(const float* __restrict__ w, bf16_t* __restrict__ wT, int K, int N) {
  __shared__ __align__(16) bf16_t tile[64][72];
  const int n0 = blockIdx.x * 64, k0 = blockIdx.y * 64;
  const int t = threadIdx.x, rr = t >> 3, c8 = (t & 7) * 8;
#pragma unroll
  for (int it = 0; it < 2; ++it) {
    const int r = rr + it * 32;
    const float4* p = (const float4*)(w + (size_t)(k0 + r) * N + n0 + c8);
    const float4 a = p[0], b = p[1];
    bf16x8 o;
    o[0] = (bf16_t)a.x; o[1] = (bf16_t)a.y; o[2] = (bf16_t)a.z; o[3] = (bf16_t)a.w;
    o[4] = (bf16_t)b.x; o[5] = (bf16_t)b.y; o[6] = (bf16_t)b.z; o[7] = (bf16_t)b.w;
    *(bf16x8*)&tile[r][c8] = o;
  }
  __syncthreads();
#pragma unroll
  for (int it = 0; it < 2; ++it) {
    const int rn = rr + it * 32;
    bf16x8 o;
#pragma unroll
    for (int j = 0; j < 8; ++j) o[j] = tile[c8 + j][rn];
    *(bf16x8*)&wT[(size_t)(n0 + rn) * K + k0 + c8] = o;
  }
}

// ---------- MFMA GEMM: C[M][N] = A[M][K] * BT[N][K]^T  (m97 recipe) ----------
template <typename TC>
__global__ __launch_bounds__(256)
void gemm_bt_kernel(const bf16_t* __restrict__ A, const bf16_t* __restrict__ BT,
                    TC* __restrict__ C, int M, int N, int K) {
  __shared__ __align__(16) bf16_t As[128 * 32];
  __shared__ __align__(16) bf16_t Bs[128 * 32];
  const int tid = threadIdx.x;
  const int lane = tid & 63, w = tid >> 6;
  const int quad = lane >> 4, l15 = lane & 15;
  const int bm = blockIdx.y * 128, bn = blockIdx.x * 128;
  const int wm = (w & 1) * 64, wn = (w >> 1) * 64;
  const int r0 = tid >> 2, c0 = tid & 3;   // staging: 4 chunks of 16B per 32-elem row

  f32x4 acc[4][4];
#pragma unroll
  for (int mt = 0; mt < 4; ++mt)
#pragma unroll
    for (int nt = 0; nt < 4; ++nt) acc[mt][nt] = zero4();

  for (int k0 = 0; k0 < K; k0 += 32) {
#pragma unroll
    for (int i = 0; i < 2; ++i) {
      const int r = r0 + i * 64;
      const int cg = (c0 ^ (r & 3)) << 3;   // XOR-swizzled source column
      gl2lds16(A + (size_t)(bm + r) * K + k0 + cg, &As[(i * 256 + w * 64) * 8]);
      gl2lds16(BT + (size_t)(bn + r) * K + k0 + cg, &Bs[(i * 256 + w * 64) * 8]);
    }
    __syncthreads();
    bf16x8 af[4], bf[4];
#pragma unroll
    for (int mt = 0; mt < 4; ++mt) {
      const int row = wm + mt * 16 + l15;
      af[mt] = *(const bf16x8*)&As[row * 32 + ((quad ^ (row & 3)) << 3)];
    }
#pragma unroll
    for (int nt = 0; nt < 4; ++nt) {
      const int row = wn + nt * 16 + l15;
      bf[nt] = *(const bf16x8*)&Bs[row * 32 + ((quad ^ (row & 3)) << 3)];
    }
#pragma unroll
    for (int mt = 0; mt < 4; ++mt)
#pragma unroll
      for (int nt = 0; nt < 4; ++nt)
        acc[mt][nt] = mfma16(af[mt], bf[nt], acc[mt][nt]);
    __syncthreads();
  }

#pragma unroll
  for (int mt = 0; mt < 4; ++mt)
#pragma unroll
    for (int nt = 0; nt < 4; ++nt)
#pragma unroll
      for (int r = 0; r < 4; ++r) {
        const int row = bm + wm + mt * 16 + quad * 4 + r;
        const int col = bn + wn + nt * 16 + l15;
        C[(size_t)row * N + col] = (TC)acc[mt][nt][r];
      }
}

// ---------- RoPE in place on bf16 qkv (q heads + k head) ----------
__global__ __launch_bounds__(128)
void rope_kernel(const int* __restrict__ pos, bf16_t* __restrict__ qkv) {
  const int bs = blockIdx.x, h = blockIdx.y, i = threadIdx.x;
  const int s = bs & (SEQ - 1);
  const float inv_freq = powf(10000.0f, -(float)i / 128.0f);
  const float ang = (float)pos[s] * inv_freq;
  float sn, cs;
  sincosf(ang, &sn, &cs);
  const size_t base = (size_t)bs * QKVN + (size_t)h * HD;
  const float x1 = (float)qkv[base + i];
  const float x2 = (float)qkv[base + 128 + i];
  qkv[base + i]       = (bf16_t)(x1 * cs - x2 * sn);
  qkv[base + 128 + i] = (bf16_t)(x2 * cs + x1 * sn);
}

// ---------- V transpose: qkv v-part [s][d] -> Vt[b][d][s] ----------
__global__ __launch_bounds__(256)
void vtrans_kernel(const bf16_t* __restrict__ qkv, bf16_t* __restrict__ Vt) {
  __shared__ __align__(16) bf16_t tile[64][72];
  const int s0 = blockIdx.x * 64, d0 = blockIdx.y * 64, b = blockIdx.z;
  const int t = threadIdx.x, rr = t >> 3, c8 = (t & 7) * 8;
#pragma unroll
  for (int it = 0; it < 2; ++it) {
    const int r = rr + it * 32;
    *(bf16x8*)&tile[r][c8] =
        *(const bf16x8*)&qkv[(size_t)(b * SEQ + s0 + r) * QKVN + 2304 + d0 + c8];
  }
  __syncthreads();
#pragma unroll
  for (int it = 0; it < 2; ++it) {
    const int dd = rr + it * 32;
    bf16x8 o;
#pragma unroll
    for (int j = 0; j < 8; ++j) o[j] = tile[c8 + j][dd];
    *(bf16x8*)&Vt[(size_t)(b * HD + d0 + dd) * SEQ + s0 + c8] = o;
  }
}

// ---------- flash attention, MFMA. Block: 4 waves x 16 q-rows = 64 q. ----------
__global__ __launch_bounds__(256)
void attn_kernel(const bf16_t* __restrict__ qkv, const bf16_t* __restrict__ Vt,
                 bf16_t* __restrict__ O) {
  __shared__ __align__(16) bf16_t Ks[64 * 256];    // [key][d], chunk-swizzled
  __shared__ __align__(16) bf16_t Vts[256 * 64];   // [d][key], chunk-swizzled
  __shared__ __align__(16) bf16_t Pl[4][16][72];   // per-wave P, padded rows

  const int tid = threadIdx.x, w = tid >> 6, lane = tid & 63;
  const int quad = lane >> 4, l15 = lane & 15;
  const int qt = 31 - (blockIdx.x >> 5);           // heavy q-tiles dispatched first
  const int bh = blockIdx.x & 31, b = bh >> 3, h = bh & 7;
  const int qb = qt * 64, q_lo = qb + w * 16;

  // Q fragments in registers (A-layout: m = l15, k = quad*8+j)
  bf16x8 qf[8];
  const bf16_t* qp = qkv + (size_t)(b * SEQ + q_lo + l15) * QKVN + (size_t)h * HD + quad * 8;
#pragma unroll
  for (int ks = 0; ks < 8; ++ks) qf[ks] = *(const bf16x8*)(qp + ks * 32);

  float mrun[4], lrun[4];
  f32x4 of[16];
#pragma unroll
  for (int r = 0; r < 4; ++r) { mrun[r] = -3e38f; lrun[r] = 0.f; }
#pragma unroll
  for (int dt = 0; dt < 16; ++dt) of[dt] = zero4();

  const int sr = tid >> 5, sc = tid & 31;  // K staging: 32 chunks/row
  const int vr = tid >> 3, vc = tid & 7;   // Vt staging: 8 chunks/row

  for (int kt = 0; kt <= qt; ++kt) {
    // ---- stage K-tile (64x256) and Vt-tile (256x64), XOR-swizzled chunks ----
#pragma unroll
    for (int i = 0; i < 8; ++i) {
      const int r = i * 8 + sr;
      gl2lds16(qkv + (size_t)(b * SEQ + kt * 64 + r) * QKVN + 2048 + ((sc ^ (r & 31)) << 3),
               &Ks[(i * 256 + w * 64) * 8]);
    }
#pragma unroll
    for (int i = 0; i < 8; ++i) {
      const int r = i * 32 + vr;
      gl2lds16(Vt + (size_t)(b * HD + r) * SEQ + kt * 64 + ((vc ^ (r & 7)) << 3),
               &Vts[(i * 256 + w * 64) * 8]);
    }
    __syncthreads();

    // ---- S = Q K^T (B-frag: n = key = l15-row of Ks, k = d contiguous) ----
    f32x4 sf[4];
#pragma unroll
    for (int nt = 0; nt < 4; ++nt) {
      f32x4 acc = zero4();
      const int row = nt * 16 + l15;
#pragma unroll
      for (int ks = 0; ks < 8; ++ks) {
        const int j = ks * 4 + quad;
        const bf16x8 kf = *(const bf16x8*)&Ks[row * 256 + ((j ^ (row & 31)) << 3)];
        acc = mfma16(qf[ks], kf, acc);
      }
      sf[nt] = acc;
    }

    // ---- scale + causal mask + online softmax (C-layout rows = quad*4+r) ----
    float mx[4];
#pragma unroll
    for (int r = 0; r < 4; ++r) {
      const int qg = q_lo + quad * 4 + r;
      float v = -3e38f;
#pragma unroll
      for (int nt = 0; nt < 4; ++nt) {
        const int kg = kt * 64 + nt * 16 + l15;
        const float s = (kg <= qg) ? sf[nt][r] * SCL : -3e38f;
        sf[nt][r] = s;
        v = fmaxf(v, s);
      }
      mx[r] = rmax16(v);
    }
    float al[4];
#pragma unroll
    for (int r = 0; r < 4; ++r) {
      const float mn = fmaxf(mrun[r], mx[r]);
      al[r] = __expf(mrun[r] - mn);
      mrun[r] = mn;
    }
#pragma unroll
    for (int r = 0; r < 4; ++r) {
      float sum = 0.f;
#pragma unroll
      for (int nt = 0; nt < 4; ++nt) {
        const float pv = __expf(sf[nt][r] - mrun[r]);
        Pl[w][quad * 4 + r][nt * 16 + l15] = (bf16_t)pv;
        sum += pv;
      }
      lrun[r] = lrun[r] * al[r] + rsum16(sum);
    }
    __asm__ volatile("s_waitcnt lgkmcnt(0)" ::: "memory");  // wave-local P handoff

    // ---- rescale O, then O += P V ----
    f32x4 av;
#pragma unroll
    for (int r = 0; r < 4; ++r) av[r] = al[r];
#pragma unroll
    for (int dt = 0; dt < 16; ++dt) of[dt] *= av;

    bf16x8 pa[2];
#pragma unroll
    for (int k2 = 0; k2 < 2; ++k2)
      pa[k2] = *(const bf16x8*)&Pl[w][l15][k2 * 32 + quad * 8];
#pragma unroll
    for (int dt = 0; dt < 16; ++dt) {
      const int row = dt * 16 + l15;
#pragma unroll
      for (int k2 = 0; k2 < 2; ++k2) {
        const int j = k2 * 4 + quad;
        const bf16x8 vf = *(const bf16x8*)&Vts[row * 64 + ((j ^ (row & 7)) << 3)];
        of[dt] = mfma16(pa[k2], vf, of[dt]);
      }
    }
    __syncthreads();
  }

  // ---- epilogue: O /= l, store bf16 [b][s][h*HD+d] ----
  f32x4 iv;
#pragma unroll
  for (int r = 0; r < 4; ++r) iv[r] = 1.0f / lrun[r];
#pragma unroll
  for (int dt = 0; dt < 16; ++dt) {
    const f32x4 o = of[dt] * iv;
#pragma unroll
    for (int r = 0; r < 4; ++r)
      O[(size_t)(b * SEQ + q_lo + quad * 4 + r) * HID + (size_t)h * HD + dt * 16 + l15] =
          (bf16_t)o[r];
  }
}

// ---------- launch ----------
extern "C" void kernel_launch(void* const* d_in, const int* in_sizes, int n_in,
                              void* d_out, int out_size, void* d_ws, size_t ws_size,
                              hipStream_t stream) {
  const float* hidden  = (const float*)d_in[0];
  const int* positions = (const int*)d_in[1];
  const float* w_qkv   = (const float*)d_in[2];
  const float* w_o     = (const float*)d_in[3];
  float* out           = (float*)d_out;

  char* ws = (char*)d_ws;
  bf16_t* hiddenB = (bf16_t*)ws; ws += (size_t)8192 * 2048 * 2;   // 33.5 MB
  bf16_t* wqkvT   = (bf16_t*)ws; ws += (size_t)2560 * 2048 * 2;   // 10.5 MB
  bf16_t* woT     = (bf16_t*)ws; ws += (size_t)2048 * 2048 * 2;   //  8.4 MB
  bf16_t* qkvB    = (bf16_t*)ws; ws += (size_t)8192 * 2560 * 2;   // 41.9 MB
  bf16_t* VtB     = (bf16_t*)ws; ws += (size_t)4 * 256 * 2048 * 2;//  4.2 MB
  bf16_t* attnB   = (bf16_t*)ws;                                  // 33.5 MB

  cvt_bf16_kernel<<<8192, 256, 0, stream>>>(hidden, hiddenB);
  transw_kernel<<<dim3(QKVN / 64, HID / 64), 256, 0, stream>>>(w_qkv, wqkvT, HID, QKVN);
  transw_kernel<<<dim3(HID / 64, HID / 64), 256, 0, stream>>>(w_o, woT, HID, HID);

  gemm_bt_kernel<bf16_t><<<dim3(QKVN / 128, 64), 256, 0, stream>>>
      (hiddenB, wqkvT, qkvB, 8192, QKVN, HID);

  rope_kernel<<<dim3(BATCH * SEQ, 9), 128, 0, stream>>>(positions, qkvB);
  vtrans_kernel<<<dim3(SEQ / 64, HD / 64, BATCH), 256, 0, stream>>>(qkvB, VtB);

  attn_kernel<<<1024, 256, 0, stream>>>(qkvB, VtB, attnB);

  gemm_bt_kernel<float><<<dim3(HID / 128, 64), 256, 0, stream>>>
      (attnB, woT, out, 8192, HID, HID);
}

// Round 4
// 537.448 us; speedup vs baseline: 9.4637x; 1.1411x over previous
//
#include <hip/hip_runtime.h>
#include <math.h>

constexpr int BATCH = 4;
constexpr int SEQ   = 2048;
constexpr int HID   = 2048;
constexpr int NHEAD = 8;
constexpr int HD    = 256;
constexpr int QKVN  = (NHEAD + 2) * HD;          // 2560
constexpr float SCL = 0.0625f;                   // 256^-0.5

typedef __bf16 bf16_t;
typedef __bf16 bf16x8 __attribute__((ext_vector_type(8)));
typedef float  f32x4  __attribute__((ext_vector_type(4)));

__device__ __forceinline__ f32x4 zero4() {
  f32x4 z; z[0] = 0.f; z[1] = 0.f; z[2] = 0.f; z[3] = 0.f; return z;
}

__device__ __forceinline__ f32x4 mfma16(bf16x8 a, bf16x8 b, f32x4 c) {
  return __builtin_amdgcn_mfma_f32_16x16x32_bf16(a, b, c, 0, 0, 0);
}

// async global->LDS, 16B per lane. lds must be wave-uniform base; HW adds lane*16.
__device__ __forceinline__ void gl2lds16(const void* g, void* lds) {
  typedef __attribute__((address_space(1))) void* gp_t;
  typedef __attribute__((address_space(3))) void* lp_t;
  __builtin_amdgcn_global_load_lds((gp_t)(size_t)g,
                                   (lp_t)(unsigned int)(size_t)lds, 16, 0, 0);
}

__device__ __forceinline__ float rmax16(float v) {
#pragma unroll
  for (int o = 1; o < 16; o <<= 1) v = fmaxf(v, __shfl_xor(v, o));
  return v;
}
__device__ __forceinline__ float rsum16(float v) {
#pragma unroll
  for (int o = 1; o < 16; o <<= 1) v += __shfl_xor(v, o);
  return v;
}

// ---------- fp32 -> bf16 bulk convert (8 elems/thread) ----------
__global__ __launch_bounds__(256)
void cvt_bf16_kernel(const float* __restrict__ in, bf16_t* __restrict__ out) {
  const int i = blockIdx.x * 256 + threadIdx.x;
  const float4 a = ((const float4*)in)[i * 2];
  const float4 b = ((const float4*)in)[i * 2 + 1];
  bf16x8 o;
  o[0] = (bf16_t)a.x; o[1] = (bf16_t)a.y; o[2] = (bf16_t)a.z; o[3] = (bf16_t)a.w;
  o[4] = (bf16_t)b.x; o[5] = (bf16_t)b.y; o[6] = (bf16_t)b.z; o[7] = (bf16_t)b.w;
  ((bf16x8*)out)[i] = o;
}

// ---------- w[K][N] fp32 -> wT[N][K] bf16, 64x64 tiles ----------
__global__ __launch_bounds__(256)
void transw_kernel(const float* __restrict__ w, bf16_t* __restrict__ wT, int K, int N) {
  __shared__ __align__(16) bf16_t tile[64][72];
  const int n0 = blockIdx.x * 64, k0 = blockIdx.y * 64;
  const int t = threadIdx.x, rr = t >> 3, c8 = (t & 7) * 8;
#pragma unroll
  for (int it = 0; it < 2; ++it) {
    const int r = rr + it * 32;
    const float4* p = (const float4*)(w + (size_t)(k0 + r) * N + n0 + c8);
    const float4 a = p[0], b = p[1];
    bf16x8 o;
    o[0] = (bf16_t)a.x; o[1] = (bf16_t)a.y; o[2] = (bf16_t)a.z; o[3] = (bf16_t)a.w;
    o[4] = (bf16_t)b.x; o[5] = (bf16_t)b.y; o[6] = (bf16_t)b.z; o[7] = (bf16_t)b.w;
    *(bf16x8*)&tile[r][c8] = o;
  }
  __syncthreads();
#pragma unroll
  for (int it = 0; it < 2; ++it) {
    const int rn = rr + it * 32;
    bf16x8 o;
#pragma unroll
    for (int j = 0; j < 8; ++j) o[j] = tile[c8 + j][rn];
    *(bf16x8*)&wT[(size_t)(n0 + rn) * K + k0 + c8] = o;
  }
}

// ---------- MFMA GEMM: C[M][N] = A[M][K] * BT[N][K]^T  (m97 recipe) ----------
template <typename TC>
__global__ __launch_bounds__(256)
void gemm_bt_kernel(const bf16_t* __restrict__ A, const bf16_t* __restrict__ BT,
                    TC* __restrict__ C, int M, int N, int K) {
  __shared__ __align__(16) bf16_t As[128 * 32];
  __shared__ __align__(16) bf16_t Bs[128 * 32];
  const int tid = threadIdx.x;
  const int lane = tid & 63, w = tid >> 6;
  const int quad = lane >> 4, l15 = lane & 15;
  const int bm = blockIdx.y * 128, bn = blockIdx.x * 128;
  const int wm = (w & 1) * 64, wn = (w >> 1) * 64;
  const int r0 = tid >> 2, c0 = tid & 3;   // staging: 4 chunks of 16B per 32-elem row

  f32x4 acc[4][4];
#pragma unroll
  for (int mt = 0; mt < 4; ++mt)
#pragma unroll
    for (int nt = 0; nt < 4; ++nt) acc[mt][nt] = zero4();

  for (int k0 = 0; k0 < K; k0 += 32) {
#pragma unroll
    for (int i = 0; i < 2; ++i) {
      const int r = r0 + i * 64;
      const int cg = (c0 ^ (r & 3)) << 3;   // XOR-swizzled source column
      gl2lds16(A + (size_t)(bm + r) * K + k0 + cg, &As[(i * 256 + w * 64) * 8]);
      gl2lds16(BT + (size_t)(bn + r) * K + k0 + cg, &Bs[(i * 256 + w * 64) * 8]);
    }
    __syncthreads();
    bf16x8 af[4], bf[4];
#pragma unroll
    for (int mt = 0; mt < 4; ++mt) {
      const int row = wm + mt * 16 + l15;
      af[mt] = *(const bf16x8*)&As[row * 32 + ((quad ^ (row & 3)) << 3)];
    }
#pragma unroll
    for (int nt = 0; nt < 4; ++nt) {
      const int row = wn + nt * 16 + l15;
      bf[nt] = *(const bf16x8*)&Bs[row * 32 + ((quad ^ (row & 3)) << 3)];
    }
#pragma unroll
    for (int mt = 0; mt < 4; ++mt)
#pragma unroll
      for (int nt = 0; nt < 4; ++nt)
        acc[mt][nt] = mfma16(af[mt], bf[nt], acc[mt][nt]);
    __syncthreads();
  }

#pragma unroll
  for (int mt = 0; mt < 4; ++mt)
#pragma unroll
    for (int nt = 0; nt < 4; ++nt)
#pragma unroll
      for (int r = 0; r < 4; ++r) {
        const int row = bm + wm + mt * 16 + quad * 4 + r;
        const int col = bn + wn + nt * 16 + l15;
        C[(size_t)row * N + col] = (TC)acc[mt][nt][r];
      }
}

// ---------- RoPE in place on bf16 qkv (q heads + k head) ----------
__global__ __launch_bounds__(128)
void rope_kernel(const int* __restrict__ pos, bf16_t* __restrict__ qkv) {
  const int bs = blockIdx.x, h = blockIdx.y, i = threadIdx.x;
  const int s = bs & (SEQ - 1);
  const float inv_freq = powf(10000.0f, -(float)i / 128.0f);
  const float ang = (float)pos[s] * inv_freq;
  float sn, cs;
  sincosf(ang, &sn, &cs);
  const size_t base = (size_t)bs * QKVN + (size_t)h * HD;
  const float x1 = (float)qkv[base + i];
  const float x2 = (float)qkv[base + 128 + i];
  qkv[base + i]       = (bf16_t)(x1 * cs - x2 * sn);
  qkv[base + 128 + i] = (bf16_t)(x2 * cs + x1 * sn);
}

// ---------- V transpose: qkv v-part [s][d] -> Vt[b][d][s] ----------
__global__ __launch_bounds__(256)
void vtrans_kernel(const bf16_t* __restrict__ qkv, bf16_t* __restrict__ Vt) {
  __shared__ __align__(16) bf16_t tile[64][72];
  const int s0 = blockIdx.x * 64, d0 = blockIdx.y * 64, b = blockIdx.z;
  const int t = threadIdx.x, rr = t >> 3, c8 = (t & 7) * 8;
#pragma unroll
  for (int it = 0; it < 2; ++it) {
    const int r = rr + it * 32;
    *(bf16x8*)&tile[r][c8] =
        *(const bf16x8*)&qkv[(size_t)(b * SEQ + s0 + r) * QKVN + 2304 + d0 + c8];
  }
  __syncthreads();
#pragma unroll
  for (int it = 0; it < 2; ++it) {
    const int dd = rr + it * 32;
    bf16x8 o;
#pragma unroll
    for (int j = 0; j < 8; ++j) o[j] = tile[c8 + j][dd];
    *(bf16x8*)&Vt[(size_t)(b * HD + d0 + dd) * SEQ + s0 + c8] = o;
  }
}

// ---------- flash attention, MQA-shared K/V staging ----------
// Block: 512 threads = 8 waves, wave w = head w. All waves share one K/V tile.
// Each block processes the complementary q-tile pair (qt, 127-qt) sequentially
// -> uniform ~33 K-tile iterations per block, 256 blocks = 1 per CU.
__global__ __launch_bounds__(512)
void attn_kernel(const bf16_t* __restrict__ qkv, const bf16_t* __restrict__ Vt,
                 bf16_t* __restrict__ O) {
  __shared__ __align__(16) bf16_t Ks[64 * 256];    // [key][d], chunk-swizzled (32 KB)
  __shared__ __align__(16) bf16_t Vts[256 * 64];   // [d][key], chunk-swizzled (32 KB)
  __shared__ __align__(16) bf16_t Pl[8][16][72];   // per-wave P, padded rows (18.4 KB)

  const int tid = threadIdx.x, w = tid >> 6, lane = tid & 63;
  const int quad = lane >> 4, l15 = lane & 15;
  const int b = blockIdx.x >> 6;                   // 4 batches x 64 pair-groups
  const int qtR = blockIdx.x & 63;
  const int h = w;

  // staging decomposition (512 threads)
  const int krow_base = w * 2 + (lane >> 5);       // + i*16 -> key row 0..63
  const int kcol = lane & 31;                      // 16B chunk within 256-d row
  const int vrow_base = w * 8 + (lane >> 3);       // + i*64 -> d row 0..255
  const int vcol = lane & 7;                       // 16B chunk within 64-key row

  for (int phase = 0; phase < 2; ++phase) {
    const int qt = phase ? (127 - qtR) : qtR;
    const int q0 = qt * 16;

    // Q fragments (A-layout: m = l15, k = quad*8+j)
    bf16x8 qf[8];
    const bf16_t* qp =
        qkv + (size_t)(b * SEQ + q0 + l15) * QKVN + (size_t)h * HD + quad * 8;
#pragma unroll
    for (int ks = 0; ks < 8; ++ks) qf[ks] = *(const bf16x8*)(qp + ks * 32);

    float mrun[4], lrun[4];
    f32x4 of[16];
#pragma unroll
    for (int r = 0; r < 4; ++r) { mrun[r] = -3e38f; lrun[r] = 0.f; }
#pragma unroll
    for (int dt = 0; dt < 16; ++dt) of[dt] = zero4();

    const int ntiles = q0 / 64 + 1;

    for (int kt = 0; kt < ntiles; ++kt) {
      // ---- stage K-tile (64x256) + Vt-tile (256x64) cooperatively ----
      const bf16_t* kbase = qkv + (size_t)(b * SEQ + kt * 64) * QKVN + 2048;
#pragma unroll
      for (int i = 0; i < 4; ++i) {
        const int r = i * 16 + krow_base;
        gl2lds16(kbase + (size_t)r * QKVN + ((kcol ^ (r & 31)) << 3),
                 &Ks[(i * 512 + w * 64) * 8]);
      }
      const bf16_t* vbase = Vt + (size_t)b * HD * SEQ + kt * 64;
#pragma unroll
      for (int i = 0; i < 4; ++i) {
        const int r = i * 64 + vrow_base;
        gl2lds16(vbase + (size_t)r * SEQ + ((vcol ^ (r & 7)) << 3),
                 &Vts[(i * 512 + w * 64) * 8]);
      }
      __syncthreads();

      // ---- S = Q K^T ----
      f32x4 sf[4];
#pragma unroll
      for (int nt = 0; nt < 4; ++nt) {
        f32x4 acc = zero4();
        const int row = nt * 16 + l15;
#pragma unroll
        for (int ks = 0; ks < 8; ++ks) {
          const int j = ks * 4 + quad;
          const bf16x8 kf = *(const bf16x8*)&Ks[row * 256 + ((j ^ (row & 31)) << 3)];
          acc = mfma16(qf[ks], kf, acc);
        }
        sf[nt] = acc;
      }

      // ---- scale + causal mask + online softmax ----
      float mx[4];
#pragma unroll
      for (int r = 0; r < 4; ++r) {
        const int qg = q0 + quad * 4 + r;
        float v = -3e38f;
#pragma unroll
        for (int nt = 0; nt < 4; ++nt) {
          const int kg = kt * 64 + nt * 16 + l15;
          const float s = (kg <= qg) ? sf[nt][r] * SCL : -3e38f;
          sf[nt][r] = s;
          v = fmaxf(v, s);
        }
        mx[r] = rmax16(v);
      }
      float al[4];
#pragma unroll
      for (int r = 0; r < 4; ++r) {
        const float mn = fmaxf(mrun[r], mx[r]);
        al[r] = __expf(mrun[r] - mn);
        mrun[r] = mn;
      }
#pragma unroll
      for (int r = 0; r < 4; ++r) {
        float sum = 0.f;
#pragma unroll
        for (int nt = 0; nt < 4; ++nt) {
          const float pv = __expf(sf[nt][r] - mrun[r]);
          Pl[w][quad * 4 + r][nt * 16 + l15] = (bf16_t)pv;
          sum += pv;
        }
        lrun[r] = lrun[r] * al[r] + rsum16(sum);
      }
      __asm__ volatile("s_waitcnt lgkmcnt(0)" ::: "memory");  // wave-local P handoff

      // ---- rescale O, then O += P V ----
      f32x4 av;
#pragma unroll
      for (int r = 0; r < 4; ++r) av[r] = al[r];
#pragma unroll
      for (int dt = 0; dt < 16; ++dt) of[dt] *= av;

      bf16x8 pa[2];
#pragma unroll
      for (int k2 = 0; k2 < 2; ++k2)
        pa[k2] = *(const bf16x8*)&Pl[w][l15][k2 * 32 + quad * 8];
#pragma unroll
      for (int dt = 0; dt < 16; ++dt) {
        const int row = dt * 16 + l15;
#pragma unroll
        for (int k2 = 0; k2 < 2; ++k2) {
          const int j = k2 * 4 + quad;
          const bf16x8 vf = *(const bf16x8*)&Vts[row * 64 + ((j ^ (row & 7)) << 3)];
          of[dt] = mfma16(pa[k2], vf, of[dt]);
        }
      }
      __syncthreads();
    }

    // ---- epilogue: O /= l, store bf16 [b][s][h*HD+d] ----
    f32x4 iv;
#pragma unroll
    for (int r = 0; r < 4; ++r) iv[r] = 1.0f / lrun[r];
#pragma unroll
    for (int dt = 0; dt < 16; ++dt) {
      const f32x4 o = of[dt] * iv;
#pragma unroll
      for (int r = 0; r < 4; ++r)
        O[(size_t)(b * SEQ + q0 + quad * 4 + r) * HID + (size_t)h * HD + dt * 16 + l15] =
            (bf16_t)o[r];
    }
  }
}

// ---------- launch ----------
extern "C" void kernel_launch(void* const* d_in, const int* in_sizes, int n_in,
                              void* d_out, int out_size, void* d_ws, size_t ws_size,
                              hipStream_t stream) {
  const float* hidden  = (const float*)d_in[0];
  const int* positions = (const int*)d_in[1];
  const float* w_qkv   = (const float*)d_in[2];
  const float* w_o     = (const float*)d_in[3];
  float* out           = (float*)d_out;

  char* ws = (char*)d_ws;
  bf16_t* hiddenB = (bf16_t*)ws; ws += (size_t)8192 * 2048 * 2;   // 33.5 MB
  bf16_t* wqkvT   = (bf16_t*)ws; ws += (size_t)2560 * 2048 * 2;   // 10.5 MB
  bf16_t* woT     = (bf16_t*)ws; ws += (size_t)2048 * 2048 * 2;   //  8.4 MB
  bf16_t* qkvB    = (bf16_t*)ws; ws += (size_t)8192 * 2560 * 2;   // 41.9 MB
  bf16_t* VtB     = (bf16_t*)ws; ws += (size_t)4 * 256 * 2048 * 2;//  4.2 MB
  bf16_t* attnB   = (bf16_t*)ws;                                  // 33.5 MB

  cvt_bf16_kernel<<<8192, 256, 0, stream>>>(hidden, hiddenB);
  transw_kernel<<<dim3(QKVN / 64, HID / 64), 256, 0, stream>>>(w_qkv, wqkvT, HID, QKVN);
  transw_kernel<<<dim3(HID / 64, HID / 64), 256, 0, stream>>>(w_o, woT, HID, HID);

  gemm_bt_kernel<bf16_t><<<dim3(QKVN / 128, 64), 256, 0, stream>>>
      (hiddenB, wqkvT, qkvB, 8192, QKVN, HID);

  rope_kernel<<<dim3(BATCH * SEQ, 9), 128, 0, stream>>>(positions, qkvB);
  vtrans_kernel<<<dim3(SEQ / 64, HD / 64, BATCH), 256, 0, stream>>>(qkvB, VtB);

  attn_kernel<<<256, 512, 0, stream>>>(qkvB, VtB, attnB);

  gemm_bt_kernel<float><<<dim3(HID / 128, 64), 256, 0, stream>>>
      (attnB, woT, out, 8192, HID, HID);
}